// Round 8
// baseline (108.351 us; speedup 1.0000x reference)
//
#include <hip/hip_runtime.h>
#include <hip/hip_fp16.h>

#define D 128
#define C 5

typedef _Float16 half8 __attribute__((ext_vector_type(8)));
typedef _Float16 half4 __attribute__((ext_vector_type(4)));
typedef float f32x4 __attribute__((ext_vector_type(4)));
typedef float f32x8 __attribute__((ext_vector_type(8)));

// ---------------------------------------------------------------------------
// Kernel 1: U = ufeat @ W1[:, :128].T ; V = ifeat @ W1[:, 128:].T  (fp16 out)
// 128 rows/block (32/wave), K=128, mfma_f32_16x16x32_f16 with SWAPPED
// operands: D = W-frag (A) x F-frag (B), so lane holds one feature row and
// 4 consecutive output cols -> packed 8-B stores (16 store instrs/wave,
// was 64 x 2-B scalar).
// Stage reads W1 fp32 directly and converts in-stage (convert kernel gone).
// LDS: W1 half as fp16, 32 KB, XOR-swizzled (byte ^= (col&7)<<4).
// ---------------------------------------------------------------------------
__global__ __launch_bounds__(256) void precompute_uv(
    const float* __restrict__ ufeat, const float* __restrict__ ifeat,
    const float* __restrict__ W1, _Float16* __restrict__ U,
    _Float16* __restrict__ V, int n_users, int n_movies, int groupsU)
{
    __shared__ _Float16 ldsB[128 * 128];   // 32 KB, swizzled fp16 W1-half
    char* lb = (char*)ldsB;

    int gid = blockIdx.x;
    const float* feat;
    _Float16* out;
    int off, base_row, nrows;
    if (gid < groupsU) {
        feat = ufeat; out = U; off = 0;
        base_row = gid * 128; nrows = n_users;
    } else {
        feat = ifeat; out = V; off = D;
        base_row = (gid - groupsU) * 128; nrows = n_movies;
    }

    int tid = threadIdx.x;
    int w = tid >> 6;
    int l = tid & 63;
    int row16 = l & 15;
    int kg = l >> 4;

    // --- F fragments first (HBM loads in flight during LDS staging).
    // B-operand layout: lane l&15 = feature row in tile, k = kg*8 + i.
    int rbase = base_row + w * 32;
    half8 afrag[2][4];   // [rowtile][kb]
    #pragma unroll
    for (int t = 0; t < 2; ++t) {
        int ra = rbase + t * 16 + row16;
        int rc = (ra < nrows) ? ra : (nrows - 1);
        const float* fp = feat + (size_t)rc * D + kg * 8;
        #pragma unroll
        for (int kb = 0; kb < 4; ++kb) {
            f32x8 f = *reinterpret_cast<const f32x8*>(&fp[kb * 32]);
            afrag[t][kb] = __builtin_convertvector(f, half8);
        }
    }

    // --- Stage W1 half (fp32 -> fp16) into LDS, swizzled.
    // lin = fp16-byte linear index in the 32 KB half; col = W1 row (output
    // col), row stride in W1 = 1024 B fp32. 256 thr x 8 iters x 16 B.
    {
        const char* wbase = (const char*)W1 + (size_t)off * 4;
        #pragma unroll
        for (int i = 0; i < 8; ++i) {
            int lin = (tid + i * 256) * 16;
            int col = lin >> 8;            // 256 fp16-bytes per col's k-range
            int within = lin & 255;        // fp16-byte offset in k
            const float* srcp = reinterpret_cast<const float*>(
                wbase + (size_t)col * 1024 + (size_t)within * 2);
            f32x8 wv = *reinterpret_cast<const f32x8*>(srcp);
            half8 hv = __builtin_convertvector(wv, half8);
            int dstb = lin ^ ((col & 7) << 4);
            *reinterpret_cast<half8*>(lb + dstb) = hv;
        }
    }
    __syncthreads();

    // --- Main loop: 8 col-tiles x 2 row-tiles, 4 MFMA each (K=128).
    #pragma unroll 2
    for (int ct = 0; ct < 8; ++ct) {
        int c = ct * 16 + row16;           // W row (= output col) this lane
        int sw = (c & 7) << 4;
        int bb = c * 256 + kg * 16;
        half8 w0 = *reinterpret_cast<const half8*>(lb + ((bb +   0) ^ sw));
        half8 w1 = *reinterpret_cast<const half8*>(lb + ((bb +  64) ^ sw));
        half8 w2 = *reinterpret_cast<const half8*>(lb + ((bb + 128) ^ sw));
        half8 w3 = *reinterpret_cast<const half8*>(lb + ((bb + 192) ^ sw));

        #pragma unroll
        for (int rt = 0; rt < 2; ++rt) {
            f32x4 acc = {0.f, 0.f, 0.f, 0.f};
            acc = __builtin_amdgcn_mfma_f32_16x16x32_f16(w0, afrag[rt][0], acc, 0, 0, 0);
            acc = __builtin_amdgcn_mfma_f32_16x16x32_f16(w1, afrag[rt][1], acc, 0, 0, 0);
            acc = __builtin_amdgcn_mfma_f32_16x16x32_f16(w2, afrag[rt][2], acc, 0, 0, 0);
            acc = __builtin_amdgcn_mfma_f32_16x16x32_f16(w3, afrag[rt][3], acc, 0, 0, 0);

            // D layout (swapped): row r = rbase+rt*16+(l&15),
            // cols = ct*16 + kg*4 + j  -> pack 4 fp16 = 8 B store.
            int r = rbase + rt * 16 + row16;
            if (r < nrows) {
                half4 hv = __builtin_convertvector(acc, half4);
                *reinterpret_cast<half4*>(&out[(size_t)r * D + ct * 16 + kg * 4]) = hv;
            }
        }
    }
}

// ---------------------------------------------------------------------------
// Kernel 2: score = relu(U[src]+V[dst]) @ W2.T via MFMA 16x16x32 f16,
// 64 edges/wave (4 groups sharing one W2 B-frag). B-frag built in-register
// from fp32 W2 (L2-hot 2.5 KB), rows >= C zeroed — no W2h buffer/kernel.
// ---------------------------------------------------------------------------
__global__ __launch_bounds__(256) void edge_mlp(
    const _Float16* __restrict__ U, const _Float16* __restrict__ V,
    const float* __restrict__ W2,
    const int* __restrict__ src, const int* __restrict__ dst,
    float* __restrict__ out, int E)
{
    int tid = threadIdx.x;
    int w = tid >> 6;
    int l = tid & 63;
    int base = blockIdx.x * 256 + w * 64;
    int row16 = l & 15;
    int kg = l >> 4;

    // B fragments from fp32 W2, zero-padded rows C..15.
    half8 bfrag[4];
    {
        int rw = (row16 < C) ? row16 : 0;
        const float* wp = &W2[(size_t)rw * D + kg * 8];
        #pragma unroll
        for (int kb = 0; kb < 4; ++kb) {
            f32x8 wv = *reinterpret_cast<const f32x8*>(&wp[kb * 32]);
            half8 h = __builtin_convertvector(wv, half8);
            bfrag[kb] = (row16 < C) ? h : (half8)(_Float16)0.f;
        }
    }

    int i64 = base + l;
    int ic = (i64 < E) ? i64 : (E - 1);
    int sv = src[ic];
    int dv = dst[ic];

    const _Float16* up[4];
    const _Float16* vp[4];
    #pragma unroll
    for (int g = 0; g < 4; ++g) {
        int sg_ = __shfl(sv, g * 16 + row16);
        int dg_ = __shfl(dv, g * 16 + row16);
        up[g] = &U[(size_t)sg_ * D + kg * 8];
        vp[g] = &V[(size_t)dg_ * D + kg * 8];
    }

    f32x4 acc[4];
    #pragma unroll
    for (int g = 0; g < 4; ++g) acc[g] = (f32x4){0.f, 0.f, 0.f, 0.f};

    #pragma unroll
    for (int kb = 0; kb < 4; ++kb) {
        half8 au0 = *reinterpret_cast<const half8*>(&up[0][kb * 32]);
        half8 av0 = *reinterpret_cast<const half8*>(&vp[0][kb * 32]);
        half8 au1 = *reinterpret_cast<const half8*>(&up[1][kb * 32]);
        half8 av1 = *reinterpret_cast<const half8*>(&vp[1][kb * 32]);
        half8 au2 = *reinterpret_cast<const half8*>(&up[2][kb * 32]);
        half8 av2 = *reinterpret_cast<const half8*>(&vp[2][kb * 32]);
        half8 au3 = *reinterpret_cast<const half8*>(&up[3][kb * 32]);
        half8 av3 = *reinterpret_cast<const half8*>(&vp[3][kb * 32]);
        half8 h0 = __builtin_elementwise_max(au0 + av0, (half8)(_Float16)0.f);
        half8 h1 = __builtin_elementwise_max(au1 + av1, (half8)(_Float16)0.f);
        half8 h2 = __builtin_elementwise_max(au2 + av2, (half8)(_Float16)0.f);
        half8 h3 = __builtin_elementwise_max(au3 + av3, (half8)(_Float16)0.f);
        acc[0] = __builtin_amdgcn_mfma_f32_16x16x32_f16(h0, bfrag[kb], acc[0], 0, 0, 0);
        acc[1] = __builtin_amdgcn_mfma_f32_16x16x32_f16(h1, bfrag[kb], acc[1], 0, 0, 0);
        acc[2] = __builtin_amdgcn_mfma_f32_16x16x32_f16(h2, bfrag[kb], acc[2], 0, 0, 0);
        acc[3] = __builtin_amdgcn_mfma_f32_16x16x32_f16(h3, bfrag[kb], acc[3], 0, 0, 0);
    }

    int col = row16;
    if (col < C) {
        #pragma unroll
        for (int g = 0; g < 4; ++g) {
            #pragma unroll
            for (int j = 0; j < 4; ++j) {
                int er = base + g * 16 + kg * 4 + j;
                if (er < E) out[(size_t)er * C + col] = acc[g][j];
            }
        }
    }
}

extern "C" void kernel_launch(void* const* d_in, const int* in_sizes, int n_in,
                              void* d_out, int out_size, void* d_ws, size_t ws_size,
                              hipStream_t stream) {
    (void)n_in; (void)out_size; (void)ws_size;
    const float* ufeat = (const float*)d_in[0];
    const float* ifeat = (const float*)d_in[1];
    const float* W1    = (const float*)d_in[2];
    const float* W2    = (const float*)d_in[3];
    const int*   src   = (const int*)d_in[4];
    const int*   dst   = (const int*)d_in[5];

    int n_users  = in_sizes[0] / D;
    int n_movies = in_sizes[1] / D;
    int E        = in_sizes[4];

    float* out = (float*)d_out;
    _Float16* Ubuf = (_Float16*)d_ws;                    // n_users*128 fp16
    _Float16* Vbuf = Ubuf + (size_t)n_users * D;         // n_movies*128 fp16

    int groupsU = (n_users + 127) / 128;
    int groupsV = (n_movies + 127) / 128;
    precompute_uv<<<groupsU + groupsV, 256, 0, stream>>>(
        ufeat, ifeat, W1, Ubuf, Vbuf, n_users, n_movies, groupsU);

    int eblocks = (E + 255) / 256;
    edge_mlp<<<eblocks, 256, 0, stream>>>(Ubuf, Vbuf, W2, src, dst, out, E);
}